// Round 7
// baseline (226.300 us; speedup 1.0000x reference)
//
#include <hip/hip_runtime.h>
#include <stdint.h>

// Problem constants
#define NROWS 8192
#define DIN   512
#define HIDN  1024
#define EMBN  64
#define NCONS 62      // EMB - N_EFF
#define NCLS  16
#define MARGINF 0.01f

typedef unsigned short u16;
typedef __attribute__((ext_vector_type(8))) short short8;   // 8 bf16 (4 VGPRs)
typedef __attribute__((ext_vector_type(4))) float floatx4;  // 4 fp32 acc

__device__ __forceinline__ u16 f32_to_bf16(float f) {
  union { float f; uint32_t u; } x; x.f = f;
  uint32_t u = x.u;
  uint32_t r = (u + 0x7FFFu + ((u >> 16) & 1u)) >> 16;  // RNE
  return (u16)r;
}

__device__ __forceinline__ float bf16_to_f32(u16 h) {
  union { uint32_t u; float f; } x; x.u = (uint32_t)h << 16;
  return x.f;
}

__device__ __forceinline__ float fast_tanh(float x) {
  float xc = fminf(fmaxf(x, -10.f), 10.f);     // clamp: avoid inf/inf
  float e = __expf(2.f * xc);
  return (e - 1.f) * __builtin_amdgcn_rcpf(e + 1.f);
}

__device__ __forceinline__ void load_lds16(const u16* g, u16* l) {
  __builtin_amdgcn_global_load_lds(
      (const __attribute__((address_space(1))) void*)g,
      (__attribute__((address_space(3))) void*)l, 16, 0, 0);
}

// ---------------------------------------------------------------------------
// Weight pre-pack: W (K x N fp32) -> 1KB tiles [nt][ku], tile = 16 n-rows x
// 32 k. Row r's k-chunk c (8 bf16 = 16B) stored at slot c ^ ((r>>1)&3) so
// B-fragment ds_read_b128 after lane-ordered global_load_lds staging aliases
// banks at most 2-way (free, m136). Tile linear index = nt*KU + ku.
// Direct-global frag read: lane for (row=l15, chunk=q) is l15*4 + (q^((l15>>1)&3)).
// ---------------------------------------------------------------------------
__device__ __forceinline__ void pack_tile(const float* __restrict__ W,
                                          u16* __restrict__ Wp,
                                          int N, int KU, int t, int lane)
{
  const int r = lane >> 2, slot = lane & 3;
  const int c = slot ^ ((r >> 1) & 3);
  const int nt = t / KU, ku = t - nt * KU;
  const int n = nt * 16 + r;
  const int kb = ku * 32 + c * 8;
  short8 v;
#pragma unroll
  for (int j = 0; j < 8; ++j) v[j] = (short)f32_to_bf16(W[(size_t)(kb + j) * N + n]);
  *(short8*)(Wp + ((size_t)t * 64 + lane) * 8) = v;
}

// ---------------------------------------------------------------------------
// One kernel for ALL independent prep:
//   blocks [0,2048): x -> A0p (MFMA-A packed bf16) + zero Ef + labels (b<32)
//   [2048,2304): pack W1   [2304,2336): pack W2
//   [2336,2368): pack W3   [2368,2624): pack W4   [2624]: zero slab
// ---------------------------------------------------------------------------
__global__ __launch_bounds__(256)
void prep_all(const float* __restrict__ x,
              const float* __restrict__ W1, const float* __restrict__ W2,
              const float* __restrict__ W3, const float* __restrict__ W4,
              u16* __restrict__ A0p, u16* __restrict__ W1p,
              u16* __restrict__ W2p, u16* __restrict__ W3p,
              u16* __restrict__ W4p, float* __restrict__ Ef,
              float* __restrict__ slab, int* __restrict__ labels)
{
  const int b = blockIdx.x;
  const int tid = threadIdx.x;
  const int tl = tid >> 6, lane = tid & 63;
  if (b < 2048) {
    Ef[b * 256 + tid] = 0.f;
    if (b < 32) {
      const int row = b * 256 + tid;
      labels[row] = (int)x[(size_t)row * 513];
    }
    const int t = b * 4 + tl;
    const int rt = t >> 4, ku = t & 15;
    const int r = lane & 15, q = lane >> 4;
    const float* src = x + (size_t)(rt * 16 + r) * 513 + 1 + ku * 32 + q * 8;
    short8 v;
#pragma unroll
    for (int j = 0; j < 8; ++j) v[j] = (short)f32_to_bf16(src[j]);
    *(short8*)(A0p + ((size_t)t * 64 + lane) * 8) = v;
  } else if (b < 2304) {
    pack_tile(W1, W1p, 1024, 16, (b - 2048) * 4 + tl, lane);
  } else if (b < 2336) {
    pack_tile(W2, W2p, 64, 32, (b - 2304) * 4 + tl, lane);
  } else if (b < 2368) {
    pack_tile(W3, W3p, 1024, 2, (b - 2336) * 4 + tl, lane);
  } else if (b < 2624) {
    pack_tile(W4, W4p, 512, 32, (b - 2368) * 4 + tl, lane);
  } else {
    for (int i = tid; i < 4096; i += 256) slab[i] = 0.f;
  }
}

// Histogram + prefix + counts in one tiny dispatch.
__global__ __launch_bounds__(256)
void make_offsets(const int* __restrict__ labels, int* __restrict__ offs,
                  int* __restrict__ cursors, int* __restrict__ counts)
{
  __shared__ int h[NCLS];
  const int tid = threadIdx.x;
  if (tid < NCLS) h[tid] = 0;
  __syncthreads();
  for (int i = tid; i < NROWS; i += 256) atomicAdd(&h[labels[i]], 1);
  __syncthreads();
  if (tid == 0) {
    int s = 0;
    for (int c = 0; c < NCLS; ++c) { counts[c] = h[c]; offs[c] = s; cursors[c] = s; s += h[c]; }
    offs[NCLS] = s;
  }
}

__global__ __launch_bounds__(256)
void scatter_idx(const int* __restrict__ labels, int* __restrict__ cursors,
                 int* __restrict__ idx)
{
  const int i = blockIdx.x * 256 + threadIdx.x;
  if (i < NROWS) {
    const int c = labels[i];
    const int p = atomicAdd(&cursors[c], 1);
    idx[p] = i;
  }
}

// ---------------------------------------------------------------------------
// Fused layer1+layer2, HID split 4 ways (grid 128x4). Unchanged from R6.
// ---------------------------------------------------------------------------
__global__ __launch_bounds__(256)
void gemm12(const u16* __restrict__ A0p, const u16* __restrict__ W1p,
            const float* __restrict__ b1, const u16* __restrict__ W2p,
            float* __restrict__ Ef)
{
  __shared__ u16 lB[2][16 * 512];   // 32 KB dbuf; reused as lW2
  __shared__ u16 Hc[4][64 * 66];    // 33 KB -> 65 KB, 2 blocks/CU

  const int tid = threadIdx.x, wave = tid >> 6, lane = tid & 63;
  const int quad = lane >> 4, l15 = lane & 15;
  const int wm = wave >> 1, wn = wave & 1;
  const int xslot = (l15 >> 1) & 3;
  const int m0 = blockIdx.x * 64;
  const int g = blockIdx.y;

  floatx4 Hacc[4][2][2];
#pragma unroll
  for (int c = 0; c < 4; ++c)
#pragma unroll
    for (int i = 0; i < 2; ++i)
#pragma unroll
      for (int j = 0; j < 2; ++j) Hacc[c][i][j] = (floatx4){0.f, 0.f, 0.f, 0.f};

#pragma unroll
  for (int u = 0; u < 4; ++u) {     // prologue: stage K-step 0
    const int jt = wave + u * 4;
    load_lds16(W1p + (size_t)((g * 16 + jt) * 16) * 512 + lane * 8, lB[0] + jt * 512);
  }
  __syncthreads();

  for (int s = 0; s < 16; ++s) {
    const int p = s & 1;
    if (s < 15) {
#pragma unroll
      for (int u = 0; u < 4; ++u) {
        const int jt = wave + u * 4;
        load_lds16(W1p + (size_t)((g * 16 + jt) * 16 + s + 1) * 512 + lane * 8,
                   lB[1 - p] + jt * 512);
      }
    }
    short8 af[2];
#pragma unroll
    for (int i = 0; i < 2; ++i)
      af[i] = *(const short8*)(A0p +
               (size_t)((blockIdx.x * 4 + wm * 2 + i) * 16 + s) * 512 + lane * 8);
#pragma unroll
    for (int c = 0; c < 4; ++c)
#pragma unroll
      for (int j = 0; j < 2; ++j) {
        const short8 bf = *(const short8*)(lB[p] + (c * 4 + wn * 2 + j) * 512
                              + l15 * 32 + ((quad ^ xslot) << 3));
#pragma unroll
        for (int i = 0; i < 2; ++i)
          Hacc[c][i][j] = __builtin_amdgcn_mfma_f32_16x16x32_bf16(af[i], bf, Hacc[c][i][j], 0, 0, 0);
      }
    __syncthreads();
  }

  u16* lW2 = &lB[0][0];
#pragma unroll
  for (int u = 0; u < 8; ++u) {
    const int t = wave * 8 + u;
    load_lds16(W2p + (size_t)((t >> 3) * 32 + g * 8 + (t & 7)) * 512 + lane * 8,
               lW2 + t * 512);
  }
#pragma unroll
  for (int c = 0; c < 4; ++c)
#pragma unroll
    for (int j = 0; j < 2; ++j) {
      const int col = wn * 32 + j * 16 + l15;
      const float bv = b1[g * 256 + c * 64 + col];
#pragma unroll
      for (int i = 0; i < 2; ++i)
#pragma unroll
        for (int r = 0; r < 4; ++r)
          Hc[c][(wm * 32 + i * 16 + quad * 4 + r) * 66 + col] =
              f32_to_bf16(fast_tanh(Hacc[c][i][j][r] + bv));
    }
  __syncthreads();

  floatx4 Eacc[2][2];
#pragma unroll
  for (int i = 0; i < 2; ++i)
#pragma unroll
    for (int j = 0; j < 2; ++j) Eacc[i][j] = (floatx4){0.f, 0.f, 0.f, 0.f};

#pragma unroll
  for (int es = 0; es < 8; ++es) {
    const int cc = es >> 1, hh = es & 1;
    short8 af2[2];
#pragma unroll
    for (int i = 0; i < 2; ++i)
      af2[i] = *(const short8*)(Hc[cc] + (wm * 32 + i * 16 + l15) * 66 + hh * 32 + quad * 8);
#pragma unroll
    for (int j = 0; j < 2; ++j) {
      const short8 bf = *(const short8*)(lW2 + ((wn * 2 + j) * 8 + es) * 512
                            + l15 * 32 + ((quad ^ xslot) << 3));
#pragma unroll
      for (int i = 0; i < 2; ++i)
        Eacc[i][j] = __builtin_amdgcn_mfma_f32_16x16x32_bf16(af2[i], bf, Eacc[i][j], 0, 0, 0);
    }
  }

#pragma unroll
  for (int i = 0; i < 2; ++i)
#pragma unroll
    for (int j = 0; j < 2; ++j) {
      const int col = wn * 32 + j * 16 + l15;
#pragma unroll
      for (int r = 0; r < 4; ++r) {
        const int row = m0 + wm * 32 + i * 16 + quad * 4 + r;
        atomicAdd(&Ef[(size_t)row * 64 + col], Eacc[i][j][r]);
      }
    }
}

// ---------------------------------------------------------------------------
// Layer3 standalone: T = tanh(Ebf @ W3 + b3), computed ONCE (was recomputed
// 4x inside fused gemm34 -> 33.5M tanh; now 8.4M). Pure-register kernel:
// A-frags direct from row-major Ebf global (16B contiguous per lane), B-frags
// direct from packed W3p via permuted lane index. NO LDS, ZERO barriers.
// T written row-major bf16 (b16 stores, 32B-segment half-coalesced; writes
// are fire-and-forget). Block = 64 rows x 256 cols, grid (4,128)=512.
// ---------------------------------------------------------------------------
__global__ __launch_bounds__(256)
void gemm3(const u16* __restrict__ Ebf, const u16* __restrict__ W3p,
           const float* __restrict__ b3, u16* __restrict__ T)
{
  const int tid = threadIdx.x, wave = tid >> 6, lane = tid & 63;
  const int quad = lane >> 4, l15 = lane & 15;
  const int wm = wave >> 1, wn = wave & 1;
  const int c0 = blockIdx.x * 256;
  const int m0 = blockIdx.y * 64;
  const int lamb = l15 * 4 + (quad ^ ((l15 >> 1) & 3));  // pack-permuted lane

  floatx4 acc[2][8];
#pragma unroll
  for (int i = 0; i < 2; ++i)
#pragma unroll
    for (int jj = 0; jj < 8; ++jj) acc[i][jj] = (floatx4){0.f, 0.f, 0.f, 0.f};

#pragma unroll
  for (int kk = 0; kk < 2; ++kk) {
    short8 af[2];
#pragma unroll
    for (int i = 0; i < 2; ++i)
      af[i] = *(const short8*)(Ebf + (size_t)(m0 + wm * 32 + i * 16 + l15) * 64
                                   + kk * 32 + quad * 8);
#pragma unroll
    for (int jj = 0; jj < 8; ++jj) {
      const int nt = (c0 >> 4) + wn * 8 + jj;
      const short8 bf = *(const short8*)(W3p + (size_t)(nt * 2 + kk) * 512 + lamb * 8);
#pragma unroll
      for (int i = 0; i < 2; ++i)
        acc[i][jj] = __builtin_amdgcn_mfma_f32_16x16x32_bf16(af[i], bf, acc[i][jj], 0, 0, 0);
    }
  }

#pragma unroll
  for (int i = 0; i < 2; ++i)
#pragma unroll
    for (int jj = 0; jj < 8; ++jj) {
      const int col = c0 + wn * 128 + jj * 16 + l15;
      const float bv = b3[col];
#pragma unroll
      for (int r = 0; r < 4; ++r) {
        const int row = m0 + wm * 32 + i * 16 + quad * 4 + r;
        T[(size_t)row * 1024 + col] = f32_to_bf16(fast_tanh(acc[i][jj][r] + bv));
      }
    }
}

// ---------------------------------------------------------------------------
// Layer4 standalone: out = T @ W4 + b4 (8.6 GF clean GEMM, no tanh).
// Block 128 rows x 64 cols, grid (8,64)=512, 2 blocks/CU. Dbuf
// global_load_lds staging: T-tiles with lane-level XOR chunk swizzle
// (chunk = (lane&3)^((lane>>3)&3)) so A-frag ds_read_b128 aliases <=2-way;
// W4p tiles natural (pre-swizzled by pack_tile). Waves 2x2 (64x32):
// 8 MFMA / 6 b128 reads per K-step, 1 barrier/step, 24 KB LDS.
// ---------------------------------------------------------------------------
__global__ __launch_bounds__(256)
void gemm4(const u16* __restrict__ T, const u16* __restrict__ W4p,
           const float* __restrict__ b4, float* __restrict__ out)
{
  __shared__ u16 lA[2][8 * 512];    // 16 KB: 8 units of 16 rows x 32 k
  __shared__ u16 lB[2][4 * 512];    // 8 KB: 4 W4p tiles

  const int tid = threadIdx.x, wave = tid >> 6, lane = tid & 63;
  const int quad = lane >> 4, l15 = lane & 15;
  const int wm = wave >> 1, wn = wave & 1;
  const int xslot = (l15 >> 1) & 3;
  const int m0 = blockIdx.y * 128;
  const int n0 = blockIdx.x * 64;
  const int srow = lane >> 2;                       // row within 16-row unit
  const int schunk = (lane & 3) ^ ((lane >> 3) & 3); // XOR chunk swizzle

  // prologue: stage step 0
#pragma unroll
  for (int u2 = 0; u2 < 2; ++u2) {
    const int u = wave * 2 + u2;
    load_lds16(T + (size_t)(m0 + u * 16 + srow) * 1024 + schunk * 8,
               lA[0] + u * 512 + lane * 8);
  }
  load_lds16(W4p + (size_t)(((n0 >> 4) + wave) * 32) * 512 + lane * 8,
             lB[0] + wave * 512);
  __syncthreads();

  floatx4 acc[4][2];
#pragma unroll
  for (int i = 0; i < 4; ++i)
#pragma unroll
    for (int j = 0; j < 2; ++j) acc[i][j] = (floatx4){0.f, 0.f, 0.f, 0.f};

  for (int s = 0; s < 32; ++s) {
    const int p = s & 1;
    if (s < 31) {                   // stage s+1 while computing s
#pragma unroll
      for (int u2 = 0; u2 < 2; ++u2) {
        const int u = wave * 2 + u2;
        load_lds16(T + (size_t)(m0 + u * 16 + srow) * 1024 + (s + 1) * 32 + schunk * 8,
                   lA[1 - p] + u * 512 + lane * 8);
      }
      load_lds16(W4p + (size_t)(((n0 >> 4) + wave) * 32 + s + 1) * 512 + lane * 8,
                 lB[1 - p] + wave * 512);
    }
    short8 af[4], bf[2];
#pragma unroll
    for (int i = 0; i < 4; ++i)
      af[i] = *(const short8*)(lA[p] + (wm * 4 + i) * 512
                               + l15 * 32 + ((quad ^ xslot) << 3));
#pragma unroll
    for (int j = 0; j < 2; ++j)
      bf[j] = *(const short8*)(lB[p] + (wn * 2 + j) * 512
                               + l15 * 32 + ((quad ^ xslot) << 3));
#pragma unroll
    for (int i = 0; i < 4; ++i)
#pragma unroll
      for (int j = 0; j < 2; ++j)
        acc[i][j] = __builtin_amdgcn_mfma_f32_16x16x32_bf16(af[i], bf[j], acc[i][j], 0, 0, 0);
    __syncthreads();
  }

#pragma unroll
  for (int i = 0; i < 4; ++i)
#pragma unroll
    for (int j = 0; j < 2; ++j) {
      const int col = n0 + wn * 32 + j * 16 + l15;
      const float bv = b4[col];
#pragma unroll
      for (int r = 0; r < 4; ++r) {
        const int row = m0 + wm * 64 + i * 16 + quad * 4 + r;
        out[(size_t)row * 512 + col] = acc[i][j][r] + bv;
      }
    }
}

// ---------------------------------------------------------------------------
// Ef (+b2) -> Ebf, per-row sq norm + per-class sums, one pass.
// ---------------------------------------------------------------------------
__global__ __launch_bounds__(256)
void stats_sq(const float* __restrict__ Ef, const float* __restrict__ b2,
              const int* __restrict__ labels, u16* __restrict__ Ebf,
              float* __restrict__ sqrow, float* __restrict__ vsum,
              float* __restrict__ Ssum)
{
  __shared__ float lv[NCLS][64];
  __shared__ float lsq[NCLS][64];
  const int tid = threadIdx.x;
  for (int i = tid; i < NCLS * 64; i += 256) {
    ((float*)lv)[i] = 0.f; ((float*)lsq)[i] = 0.f;
  }
  __syncthreads();

  const int wave = tid >> 6, lane = tid & 63;
  const float bv = b2[lane];
  const int base = blockIdx.x * 64 + wave * 16;
  for (int r = 0; r < 16; ++r) {
    const int row = base + r;
    const int c = labels[row];
    const u16 h = f32_to_bf16(Ef[(size_t)row * 64 + lane] + bv);
    Ebf[(size_t)row * 64 + lane] = h;
    float v = bf16_to_f32(h);
    if (lane < 2) v = 0.f;
    const float v2 = v * v;
    atomicAdd(&lv[c][lane], v);
    atomicAdd(&lsq[c][lane], v2);
    float s = v2;
    for (int o = 32; o > 0; o >>= 1) s += __shfl_xor(s, o);
    if (lane == 0) sqrow[row] = s;
  }
  __syncthreads();

  for (int i = tid; i < NCLS * 64; i += 256) {
    const int c = i >> 6, k = i & 63;
    if (k >= 2) atomicAdd(&vsum[c * NCONS + k - 2], lv[c][k]);
  }
  if (tid < NCLS) {
    float s = 0.f;
    for (int k = 0; k < 64; ++k) s += lsq[tid][k];
    atomicAdd(&Ssum[tid], s);
  }
}

// ---------------------------------------------------------------------------
// Same-class pairwise hinge via bf16 MFMA gram (verified numerics since R2).
// ---------------------------------------------------------------------------
__global__ __launch_bounds__(256)
void pairwise_mfma(const u16* __restrict__ Ebf, const float* __restrict__ sqrow,
                   const int* __restrict__ idx, const int* __restrict__ offs,
                   float* __restrict__ pair_sum)
{
  const int cls = blockIdx.y;
  int p = blockIdx.x, ti = 0, cnt = 16;
  while (p >= cnt) { p -= cnt; ++ti; --cnt; }   // block-uniform scalar decode
  const int tj = ti + p;

  const int start = offs[cls];
  const int n = offs[cls + 1] - start;
  if (ti * 64 >= n || tj * 64 >= n) return;

  constexpr int LDA = 66;
  __shared__ u16 Li[64 * LDA];
  __shared__ u16 Lj[64 * LDA];
  __shared__ float sqI[64], sqJ[64];

  const int tid = threadIdx.x;
  for (int e = tid; e < 1024; e += 256) {
    const int t = e >> 9;
    const int row = (e >> 3) & 63;
    const int ch = e & 7;
    const int g = (t ? tj : ti) * 64 + row;
    short8 v = (short8)0;
    if (g < n) {
      v = *(const short8*)(Ebf + (size_t)idx[start + g] * EMBN + ch * 8);
      if (ch == 0) { v[0] = 0; v[1] = 0; }
    }
    *(short8*)((t ? Lj : Li) + row * LDA + ch * 8) = v;
  }
  if (tid < 128) {
    const int t = tid >> 6, row = tid & 63;
    const int g = (t ? tj : ti) * 64 + row;
    (t ? sqJ : sqI)[row] = (g < n) ? sqrow[idx[start + g]] : 0.f;
  }
  __syncthreads();

  const int wave = tid >> 6, lane = tid & 63;
  const int wm = wave >> 1, wn = wave & 1;
  const int quad = lane >> 4, l15 = lane & 15;

  floatx4 acc[2][2];
#pragma unroll
  for (int i = 0; i < 2; ++i)
#pragma unroll
    for (int j = 0; j < 2; ++j) acc[i][j] = (floatx4){0.f, 0.f, 0.f, 0.f};

#pragma unroll
  for (int ks = 0; ks < 2; ++ks) {
    short8 af[2], bf[2];
#pragma unroll
    for (int i = 0; i < 2; ++i)
      af[i] = *(const short8*)(Li + (wm * 32 + i * 16 + l15) * LDA + ks * 32 + quad * 8);
#pragma unroll
    for (int j = 0; j < 2; ++j)
      bf[j] = *(const short8*)(Lj + (wn * 32 + j * 16 + l15) * LDA + ks * 32 + quad * 8);
#pragma unroll
    for (int i = 0; i < 2; ++i)
#pragma unroll
      for (int j = 0; j < 2; ++j)
        acc[i][j] = __builtin_amdgcn_mfma_f32_16x16x32_bf16(af[i], bf[j], acc[i][j], 0, 0, 0);
  }

  float local = 0.f;
#pragma unroll
  for (int i = 0; i < 2; ++i)
#pragma unroll
    for (int j = 0; j < 2; ++j)
#pragma unroll
      for (int r = 0; r < 4; ++r) {
        const int row = wm * 32 + i * 16 + quad * 4 + r;
        const int col = wn * 32 + j * 16 + l15;
        const int gi = ti * 64 + row, gj = tj * 64 + col;
        if (gi < n && gj < n && gi != gj) {
          const float D = (sqI[row] + sqJ[col] - 2.f * acc[i][j][r]) * (1.f / 62.f);
          local += fmaxf(0.f, MARGINF - D);
        }
      }
  if (ti < tj) local *= 2.f;

  __shared__ float red[256];
  red[tid] = local;
  __syncthreads();
  for (int st = 128; st > 0; st >>= 1) {
    if (tid < st) red[tid] += red[tid + st];
    __syncthreads();
  }
  if (tid == 0) atomicAdd(pair_sum, red[0]);
}

__device__ __forceinline__ double block_reduce_d(double v, double* red, int tid) {
  red[tid] = v;
  __syncthreads();
  for (int st = 128; st > 0; st >>= 1) {
    if (tid < st) red[tid] += red[tid + st];
    __syncthreads();
  }
  const double r = red[0];
  __syncthreads();
  return r;
}

// C_sim (factored, no N^2) and C_diff from pair_sum + analytic diagonal.
__global__ __launch_bounds__(256)
void finalize(const float* __restrict__ vsum, const float* __restrict__ Ssum,
              const int* __restrict__ counts, const float* __restrict__ pair_sum,
              float* __restrict__ out2)
{
  const int tid = threadIdx.x;
  __shared__ double red[256];

  double v = 0.0;
  if (tid < NCLS) v = (double)Ssum[tid] * (double)(NROWS - counts[tid]);
  const double t1 = block_reduce_d(v, red, tid);            // sum_c S_c (N - n_c)

  v = 0.0;
  if (tid < NCLS) { const double nc = (double)counts[tid]; v = nc * nc; }
  const double n_same = block_reduce_d(v, red, tid);        // sum n_c^2

  v = 0.0;
  for (int i = tid; i < NCLS * NCONS; i += 256) { const double w = vsum[i]; v += w * w; }
  const double t2 = block_reduce_d(v, red, tid);            // sum_c |v_c|^2

  v = 0.0;
  if (tid < NCONS) {
    double Vk = 0.0;
    for (int c = 0; c < NCLS; ++c) Vk += (double)vsum[c * NCONS + tid];
    v = Vk * Vk;
  }
  const double t3 = block_reduce_d(v, red, tid);            // |V|^2

  if (tid == 0) {
    const double n_diff = (double)NROWS * (double)NROWS - n_same;
    const double sim = 2.0 * t1 - 2.0 * (t3 - t2);
    const double C_sim = sim / 62.0 / (n_diff + 1.0);
    const double C_diff = ((double)pair_sum[0] + (double)NROWS * (double)MARGINF)
                          / (n_same + 1.0);
    out2[0] = (float)C_sim;
    out2[1] = (float)C_diff;
  }
}

// ---------------------------------------------------------------------------
// ws_size ~256 MB (confirmed by R5 fill WRITE_SIZE = 256 MB). Flat 30.4 MB.
// 9 dispatches.
// ---------------------------------------------------------------------------
extern "C" void kernel_launch(void* const* d_in, const int* in_sizes, int n_in,
                              void* d_out, int out_size, void* d_ws, size_t ws_size,
                              hipStream_t stream)
{
  const float* x  = (const float*)d_in[0];
  const float* W1 = (const float*)d_in[1];
  const float* b1 = (const float*)d_in[2];
  const float* W2 = (const float*)d_in[3];
  const float* b2 = (const float*)d_in[4];
  const float* W3 = (const float*)d_in[5];
  const float* b3 = (const float*)d_in[6];
  const float* W4 = (const float*)d_in[7];
  const float* b4 = (const float*)d_in[8];
  float* out = (float*)d_out;

  char* ws = (char*)d_ws;
  const size_t KB = 1024, MB = 1ull << 20;
  u16* A0p    = (u16*)(ws + 0);                    // 8 MB packed A
  u16* W1p    = (u16*)(ws + 8 * MB);               // 1 MB
  u16* W2p    = (u16*)(ws + 9 * MB);               // 128 KB
  u16* W3p    = (u16*)(ws + 9 * MB + 128 * KB);    // 128 KB
  u16* W4p    = (u16*)(ws + 9 * MB + 256 * KB);    // 1 MB
  float* Ef   = (float*)(ws + 10 * MB + 256 * KB); // 2 MB fp32 (atomic target)
  u16* Ebf    = (u16*)(ws + 12 * MB + 256 * KB);   // 1 MB
  int* labels = (int*)(ws + 13 * MB + 256 * KB);   // 32 KB
  int* idx    = (int*)(ws + 13 * MB + 288 * KB);   // 32 KB
  float* slab = (float*)(ws + 13 * MB + 320 * KB); // 16 KB (zeroed in prep_all)
  int*   counts  = (int*)slab;                     // [0,16)
  int*   offs    = counts + 16;                    // [16,33)
  int*   cursors = counts + 64;                    // [64,80)
  float* Ssum    = (float*)(counts + 96);          // 16
  float* psum    = (float*)(counts + 128);         // 1
  float* vsum    = (float*)(counts + 256);         // 992
  float* sqrow = (float*)(ws + 13 * MB + 336 * KB);// 32 KB
  u16* T      = (u16*)(ws + 14 * MB);              // 16 MB (8192 x 1024 bf16)
  (void)in_sizes; (void)n_in; (void)out_size; (void)ws_size;

  prep_all<<<dim3(2625), dim3(256), 0, stream>>>(x, W1, W2, W3, W4,
                                                 A0p, W1p, W2p, W3p, W4p,
                                                 Ef, slab, labels);
  make_offsets<<<dim3(1), dim3(256), 0, stream>>>(labels, offs, cursors, counts);
  scatter_idx<<<dim3(32), dim3(256), 0, stream>>>(labels, cursors, idx);

  gemm12<<<dim3(128, 4), dim3(256), 0, stream>>>(A0p, W1p, b1, W2p, Ef);
  stats_sq<<<dim3(128), dim3(256), 0, stream>>>(Ef, b2, labels, Ebf, sqrow, vsum, Ssum);
  gemm3<<<dim3(4, 128), dim3(256), 0, stream>>>(Ebf, W3p, b3, T);
  gemm4<<<dim3(8, 64), dim3(256), 0, stream>>>(T, W4p, b4, out);
  pairwise_mfma<<<dim3(136, 16), dim3(256), 0, stream>>>(Ebf, sqrow, idx, offs, psum);
  finalize<<<dim3(1), dim3(256), 0, stream>>>(vsum, Ssum, counts, psum,
                                              out + (size_t)NROWS * DIN);
}

// Round 8
// 199.693 us; speedup vs baseline: 1.1332x; 1.1332x over previous
//
#include <hip/hip_runtime.h>
#include <stdint.h>

// Problem constants
#define NROWS 8192
#define DIN   512
#define HIDN  1024
#define EMBN  64
#define NCONS 62      // EMB - N_EFF
#define NCLS  16
#define MARGINF 0.01f

typedef unsigned short u16;
typedef __attribute__((ext_vector_type(8))) short short8;   // 8 bf16 (4 VGPRs)
typedef __attribute__((ext_vector_type(4))) float floatx4;  // 4 fp32 acc

__device__ __forceinline__ u16 f32_to_bf16(float f) {
  union { float f; uint32_t u; } x; x.f = f;
  uint32_t u = x.u;
  uint32_t r = (u + 0x7FFFu + ((u >> 16) & 1u)) >> 16;  // RNE
  return (u16)r;
}

__device__ __forceinline__ float bf16_to_f32(u16 h) {
  union { uint32_t u; float f; } x; x.u = (uint32_t)h << 16;
  return x.f;
}

__device__ __forceinline__ float fast_tanh(float x) {
  float xc = fminf(fmaxf(x, -10.f), 10.f);     // clamp: avoid inf/inf
  float e = __expf(2.f * xc);
  return (e - 1.f) * __builtin_amdgcn_rcpf(e + 1.f);
}

__device__ __forceinline__ void load_lds16(const u16* g, u16* l) {
  __builtin_amdgcn_global_load_lds(
      (const __attribute__((address_space(1))) void*)g,
      (__attribute__((address_space(3))) void*)l, 16, 0, 0);
}

// ---------------------------------------------------------------------------
// Weight pre-pack: W (K x N fp32) -> 1KB tiles [nt][ku], tile = 16 n-rows x
// 32 k. Row r's k-chunk c (8 bf16 = 16B) stored at slot c ^ ((r>>1)&3) so
// B-fragment ds_read_b128 after lane-ordered global_load_lds staging aliases
// banks at most 2-way (free, m136). Tile linear index = nt*KU + ku.
// Direct-global frag read: lane for (row=l15, chunk=q) is l15*4 + (q^((l15>>1)&3)).
// ---------------------------------------------------------------------------
__device__ __forceinline__ void pack_tile(const float* __restrict__ W,
                                          u16* __restrict__ Wp,
                                          int N, int KU, int t, int lane)
{
  const int r = lane >> 2, slot = lane & 3;
  const int c = slot ^ ((r >> 1) & 3);
  const int nt = t / KU, ku = t - nt * KU;
  const int n = nt * 16 + r;
  const int kb = ku * 32 + c * 8;
  short8 v;
#pragma unroll
  for (int j = 0; j < 8; ++j) v[j] = (short)f32_to_bf16(W[(size_t)(kb + j) * N + n]);
  *(short8*)(Wp + ((size_t)t * 64 + lane) * 8) = v;
}

// ---------------------------------------------------------------------------
// One kernel for ALL independent prep:
//   blocks [0,2048): x -> A0p (MFMA-A packed bf16) + labels (b<32)
//   [2048,2304): pack W1   [2304,2336): pack W2
//   [2336,2368): pack W3   [2368,2624): pack W4   [2624]: zero slab
// (Ef pre-zero removed: gemm12 no longer uses atomics.)
// ---------------------------------------------------------------------------
__global__ __launch_bounds__(256)
void prep_all(const float* __restrict__ x,
              const float* __restrict__ W1, const float* __restrict__ W2,
              const float* __restrict__ W3, const float* __restrict__ W4,
              u16* __restrict__ A0p, u16* __restrict__ W1p,
              u16* __restrict__ W2p, u16* __restrict__ W3p,
              u16* __restrict__ W4p, float* __restrict__ slab,
              int* __restrict__ labels)
{
  const int b = blockIdx.x;
  const int tid = threadIdx.x;
  const int tl = tid >> 6, lane = tid & 63;
  if (b < 2048) {
    if (b < 32) {
      const int row = b * 256 + tid;
      labels[row] = (int)x[(size_t)row * 513];
    }
    const int t = b * 4 + tl;
    const int rt = t >> 4, ku = t & 15;
    const int r = lane & 15, q = lane >> 4;
    const float* src = x + (size_t)(rt * 16 + r) * 513 + 1 + ku * 32 + q * 8;
    short8 v;
#pragma unroll
    for (int j = 0; j < 8; ++j) v[j] = (short)f32_to_bf16(src[j]);
    *(short8*)(A0p + ((size_t)t * 64 + lane) * 8) = v;
  } else if (b < 2304) {
    pack_tile(W1, W1p, 1024, 16, (b - 2048) * 4 + tl, lane);
  } else if (b < 2336) {
    pack_tile(W2, W2p, 64, 32, (b - 2304) * 4 + tl, lane);
  } else if (b < 2368) {
    pack_tile(W3, W3p, 1024, 2, (b - 2336) * 4 + tl, lane);
  } else if (b < 2624) {
    pack_tile(W4, W4p, 512, 32, (b - 2368) * 4 + tl, lane);
  } else {
    for (int i = tid; i < 4096; i += 256) slab[i] = 0.f;
  }
}

// ---------------------------------------------------------------------------
// Histogram + prefix + scatter in ONE single-block dispatch (was 2 kernels).
// LDS cursors; order within a class is arbitrary (pairwise doesn't care).
// ---------------------------------------------------------------------------
__global__ __launch_bounds__(256)
void group_rows(const int* __restrict__ labels, int* __restrict__ offs,
                int* __restrict__ counts, int* __restrict__ idx)
{
  __shared__ int h[NCLS], cur[NCLS];
  const int tid = threadIdx.x;
  if (tid < NCLS) h[tid] = 0;
  __syncthreads();
  for (int i = tid; i < NROWS; i += 256) atomicAdd(&h[labels[i]], 1);
  __syncthreads();
  if (tid == 0) {
    int s = 0;
    for (int c = 0; c < NCLS; ++c) {
      counts[c] = h[c]; offs[c] = s; cur[c] = s; s += h[c];
    }
    offs[NCLS] = s;
  }
  __syncthreads();
  for (int i = tid; i < NROWS; i += 256) {
    const int p = atomicAdd(&cur[labels[i]], 1);
    idx[p] = i;
  }
}

// ---------------------------------------------------------------------------
// Fused layer1+layer2, HID split 4 ways (grid 128x4). Same as R6/R7 except
// the epilogue: partial E written to a PRIVATE per-g buffer with plain
// stores (was 2M device-scope fp32 atomicAdds with 4-way cross-XCD cache-line
// contention). stats_sq sums the 4 partials.
// ---------------------------------------------------------------------------
__global__ __launch_bounds__(256)
void gemm12(const u16* __restrict__ A0p, const u16* __restrict__ W1p,
            const float* __restrict__ b1, const u16* __restrict__ W2p,
            float* __restrict__ Ef4)
{
  __shared__ u16 lB[2][16 * 512];   // 32 KB dbuf; reused as lW2
  __shared__ u16 Hc[4][64 * 66];    // 33 KB -> 65 KB, 2 blocks/CU

  const int tid = threadIdx.x, wave = tid >> 6, lane = tid & 63;
  const int quad = lane >> 4, l15 = lane & 15;
  const int wm = wave >> 1, wn = wave & 1;
  const int xslot = (l15 >> 1) & 3;
  const int m0 = blockIdx.x * 64;
  const int g = blockIdx.y;

  floatx4 Hacc[4][2][2];
#pragma unroll
  for (int c = 0; c < 4; ++c)
#pragma unroll
    for (int i = 0; i < 2; ++i)
#pragma unroll
      for (int j = 0; j < 2; ++j) Hacc[c][i][j] = (floatx4){0.f, 0.f, 0.f, 0.f};

#pragma unroll
  for (int u = 0; u < 4; ++u) {     // prologue: stage K-step 0
    const int jt = wave + u * 4;
    load_lds16(W1p + (size_t)((g * 16 + jt) * 16) * 512 + lane * 8, lB[0] + jt * 512);
  }
  __syncthreads();

  for (int s = 0; s < 16; ++s) {
    const int p = s & 1;
    if (s < 15) {
#pragma unroll
      for (int u = 0; u < 4; ++u) {
        const int jt = wave + u * 4;
        load_lds16(W1p + (size_t)((g * 16 + jt) * 16 + s + 1) * 512 + lane * 8,
                   lB[1 - p] + jt * 512);
      }
    }
    short8 af[2];
#pragma unroll
    for (int i = 0; i < 2; ++i)
      af[i] = *(const short8*)(A0p +
               (size_t)((blockIdx.x * 4 + wm * 2 + i) * 16 + s) * 512 + lane * 8);
#pragma unroll
    for (int c = 0; c < 4; ++c)
#pragma unroll
      for (int j = 0; j < 2; ++j) {
        const short8 bf = *(const short8*)(lB[p] + (c * 4 + wn * 2 + j) * 512
                              + l15 * 32 + ((quad ^ xslot) << 3));
#pragma unroll
        for (int i = 0; i < 2; ++i)
          Hacc[c][i][j] = __builtin_amdgcn_mfma_f32_16x16x32_bf16(af[i], bf, Hacc[c][i][j], 0, 0, 0);
      }
    __syncthreads();
  }

  u16* lW2 = &lB[0][0];
#pragma unroll
  for (int u = 0; u < 8; ++u) {
    const int t = wave * 8 + u;
    load_lds16(W2p + (size_t)((t >> 3) * 32 + g * 8 + (t & 7)) * 512 + lane * 8,
               lW2 + t * 512);
  }
#pragma unroll
  for (int c = 0; c < 4; ++c)
#pragma unroll
    for (int j = 0; j < 2; ++j) {
      const int col = wn * 32 + j * 16 + l15;
      const float bv = b1[g * 256 + c * 64 + col];
#pragma unroll
      for (int i = 0; i < 2; ++i)
#pragma unroll
        for (int r = 0; r < 4; ++r)
          Hc[c][(wm * 32 + i * 16 + quad * 4 + r) * 66 + col] =
              f32_to_bf16(fast_tanh(Hacc[c][i][j][r] + bv));
    }
  __syncthreads();

  floatx4 Eacc[2][2];
#pragma unroll
  for (int i = 0; i < 2; ++i)
#pragma unroll
    for (int j = 0; j < 2; ++j) Eacc[i][j] = (floatx4){0.f, 0.f, 0.f, 0.f};

#pragma unroll
  for (int es = 0; es < 8; ++es) {
    const int cc = es >> 1, hh = es & 1;
    short8 af2[2];
#pragma unroll
    for (int i = 0; i < 2; ++i)
      af2[i] = *(const short8*)(Hc[cc] + (wm * 32 + i * 16 + l15) * 66 + hh * 32 + quad * 8);
#pragma unroll
    for (int j = 0; j < 2; ++j) {
      const short8 bf = *(const short8*)(lW2 + ((wn * 2 + j) * 8 + es) * 512
                            + l15 * 32 + ((quad ^ xslot) << 3));
#pragma unroll
      for (int i = 0; i < 2; ++i)
        Eacc[i][j] = __builtin_amdgcn_mfma_f32_16x16x32_bf16(af2[i], bf, Eacc[i][j], 0, 0, 0);
    }
  }

  float* Efg = Ef4 + (size_t)g * NROWS * 64;   // private partial buffer
#pragma unroll
  for (int i = 0; i < 2; ++i)
#pragma unroll
    for (int j = 0; j < 2; ++j) {
      const int col = wn * 32 + j * 16 + l15;
#pragma unroll
      for (int r = 0; r < 4; ++r) {
        const int row = m0 + wm * 32 + i * 16 + quad * 4 + r;
        Efg[(size_t)row * 64 + col] = Eacc[i][j][r];
      }
    }
}

// ---------------------------------------------------------------------------
// Layer3 standalone: T = tanh(Ebf @ W3 + b3). Pure-register, no LDS, zero
// barriers. Unchanged from R7.
// ---------------------------------------------------------------------------
__global__ __launch_bounds__(256)
void gemm3(const u16* __restrict__ Ebf, const u16* __restrict__ W3p,
           const float* __restrict__ b3, u16* __restrict__ T)
{
  const int tid = threadIdx.x, wave = tid >> 6, lane = tid & 63;
  const int quad = lane >> 4, l15 = lane & 15;
  const int wm = wave >> 1, wn = wave & 1;
  const int c0 = blockIdx.x * 256;
  const int m0 = blockIdx.y * 64;
  const int lamb = l15 * 4 + (quad ^ ((l15 >> 1) & 3));  // pack-permuted lane

  floatx4 acc[2][8];
#pragma unroll
  for (int i = 0; i < 2; ++i)
#pragma unroll
    for (int jj = 0; jj < 8; ++jj) acc[i][jj] = (floatx4){0.f, 0.f, 0.f, 0.f};

#pragma unroll
  for (int kk = 0; kk < 2; ++kk) {
    short8 af[2];
#pragma unroll
    for (int i = 0; i < 2; ++i)
      af[i] = *(const short8*)(Ebf + (size_t)(m0 + wm * 32 + i * 16 + l15) * 64
                                   + kk * 32 + quad * 8);
#pragma unroll
    for (int jj = 0; jj < 8; ++jj) {
      const int nt = (c0 >> 4) + wn * 8 + jj;
      const short8 bf = *(const short8*)(W3p + (size_t)(nt * 2 + kk) * 512 + lamb * 8);
#pragma unroll
      for (int i = 0; i < 2; ++i)
        acc[i][jj] = __builtin_amdgcn_mfma_f32_16x16x32_bf16(af[i], bf, acc[i][jj], 0, 0, 0);
    }
  }

#pragma unroll
  for (int i = 0; i < 2; ++i)
#pragma unroll
    for (int jj = 0; jj < 8; ++jj) {
      const int col = c0 + wn * 128 + jj * 16 + l15;
      const float bv = b3[col];
#pragma unroll
      for (int r = 0; r < 4; ++r) {
        const int row = m0 + wm * 32 + i * 16 + quad * 4 + r;
        T[(size_t)row * 1024 + col] = f32_to_bf16(fast_tanh(acc[i][jj][r] + bv));
      }
    }
}

// ---------------------------------------------------------------------------
// Layer4 standalone: out = T @ W4 + b4. BK=64 double-buffer: 16 barriers
// (was 32), 16 MFMA per wave-step vs 12 ds_read_b128. Block 128x64, grid
// (8,64)=512, 48 KB LDS. T staged with XOR chunk swizzle (<=2-way alias).
// ---------------------------------------------------------------------------
__global__ __launch_bounds__(256)
void gemm4(const u16* __restrict__ T, const u16* __restrict__ W4p,
           const float* __restrict__ b4, float* __restrict__ out)
{
  __shared__ u16 lA[2][16 * 512];   // 32 KB: 16 units (16 rows x 32 k)
  __shared__ u16 lB[2][8 * 512];    // 16 KB: 8 W4p tiles

  const int tid = threadIdx.x, wave = tid >> 6, lane = tid & 63;
  const int quad = lane >> 4, l15 = lane & 15;
  const int wm = wave >> 1, wn = wave & 1;
  const int xslot = (l15 >> 1) & 3;
  const int m0 = blockIdx.y * 128;
  const int n0 = blockIdx.x * 64;
  const int srow = lane >> 2;                        // row within 16-row unit
  const int schunk = (lane & 3) ^ ((lane >> 3) & 3); // XOR chunk swizzle

  // stage K-chunk s into buffer buf (24 units: 16 A + 8 B; 6 per wave)
  auto stage = [&](int s, int buf) {
#pragma unroll
    for (int q = 0; q < 6; ++q) {
      const int u = wave + q * 4;
      if (u < 16) {
        const int rg = u >> 1, kh = u & 1;
        load_lds16(T + (size_t)(m0 + rg * 16 + srow) * 1024 + s * 64 + kh * 32 + schunk * 8,
                   (buf ? lA[1] : lA[0]) + u * 512 + lane * 8);
      } else {
        const int v = u - 16, nt = v >> 1, kh = v & 1;
        load_lds16(W4p + (size_t)(((n0 >> 4) + nt) * 32 + s * 2 + kh) * 512 + lane * 8,
                   (buf ? lB[1] : lB[0]) + v * 512 + lane * 8);
      }
    }
  };

  stage(0, 0);
  __syncthreads();

  floatx4 acc[4][2];
#pragma unroll
  for (int i = 0; i < 4; ++i)
#pragma unroll
    for (int j = 0; j < 2; ++j) acc[i][j] = (floatx4){0.f, 0.f, 0.f, 0.f};

  for (int s = 0; s < 16; ++s) {
    const int p = s & 1;
    if (s < 15) stage(s + 1, 1 - p);
#pragma unroll
    for (int kk = 0; kk < 2; ++kk) {
      short8 af[4], bf[2];
#pragma unroll
      for (int i = 0; i < 4; ++i)
        af[i] = *(const short8*)(lA[p] + ((wm * 4 + i) * 2 + kk) * 512
                                 + l15 * 32 + ((quad ^ xslot) << 3));
#pragma unroll
      for (int j = 0; j < 2; ++j)
        bf[j] = *(const short8*)(lB[p] + ((wn * 2 + j) * 2 + kk) * 512
                                 + l15 * 32 + ((quad ^ xslot) << 3));
#pragma unroll
      for (int i = 0; i < 4; ++i)
#pragma unroll
        for (int j = 0; j < 2; ++j)
          acc[i][j] = __builtin_amdgcn_mfma_f32_16x16x32_bf16(af[i], bf[j], acc[i][j], 0, 0, 0);
    }
    __syncthreads();
  }

#pragma unroll
  for (int i = 0; i < 4; ++i)
#pragma unroll
    for (int j = 0; j < 2; ++j) {
      const int col = n0 + wn * 32 + j * 16 + l15;
      const float bv = b4[col];
#pragma unroll
      for (int r = 0; r < 4; ++r) {
        const int row = m0 + wm * 64 + i * 16 + quad * 4 + r;
        out[(size_t)row * 512 + col] = acc[i][j][r] + bv;
      }
    }
}

// ---------------------------------------------------------------------------
// Sum 4 E-partials (+b2) -> Ebf, per-row sq norm + per-class sums, one pass.
// ---------------------------------------------------------------------------
__global__ __launch_bounds__(256)
void stats_sq(const float* __restrict__ Ef4, const float* __restrict__ b2,
              const int* __restrict__ labels, u16* __restrict__ Ebf,
              float* __restrict__ sqrow, float* __restrict__ vsum,
              float* __restrict__ Ssum)
{
  __shared__ float lv[NCLS][64];
  __shared__ float lsq[NCLS][64];
  const int tid = threadIdx.x;
  for (int i = tid; i < NCLS * 64; i += 256) {
    ((float*)lv)[i] = 0.f; ((float*)lsq)[i] = 0.f;
  }
  __syncthreads();

  const int wave = tid >> 6, lane = tid & 63;
  const float bv = b2[lane];
  const int base = blockIdx.x * 64 + wave * 16;
  for (int r = 0; r < 16; ++r) {
    const int row = base + r;
    const int c = labels[row];
    float acc = bv;
#pragma unroll
    for (int g = 0; g < 4; ++g)
      acc += Ef4[((size_t)g * NROWS + row) * 64 + lane];
    const u16 h = f32_to_bf16(acc);
    Ebf[(size_t)row * 64 + lane] = h;
    float v = bf16_to_f32(h);
    if (lane < 2) v = 0.f;
    const float v2 = v * v;
    atomicAdd(&lv[c][lane], v);
    atomicAdd(&lsq[c][lane], v2);
    float s = v2;
    for (int o = 32; o > 0; o >>= 1) s += __shfl_xor(s, o);
    if (lane == 0) sqrow[row] = s;
  }
  __syncthreads();

  for (int i = tid; i < NCLS * 64; i += 256) {
    const int c = i >> 6, k = i & 63;
    if (k >= 2) atomicAdd(&vsum[c * NCONS + k - 2], lv[c][k]);
  }
  if (tid < NCLS) {
    float s = 0.f;
    for (int k = 0; k < 64; ++k) s += lsq[tid][k];
    atomicAdd(&Ssum[tid], s);
  }
}

// ---------------------------------------------------------------------------
// Same-class pairwise hinge via bf16 MFMA gram (verified numerics since R2).
// ---------------------------------------------------------------------------
__global__ __launch_bounds__(256)
void pairwise_mfma(const u16* __restrict__ Ebf, const float* __restrict__ sqrow,
                   const int* __restrict__ idx, const int* __restrict__ offs,
                   float* __restrict__ pair_sum)
{
  const int cls = blockIdx.y;
  int p = blockIdx.x, ti = 0, cnt = 16;
  while (p >= cnt) { p -= cnt; ++ti; --cnt; }   // block-uniform scalar decode
  const int tj = ti + p;

  const int start = offs[cls];
  const int n = offs[cls + 1] - start;
  if (ti * 64 >= n || tj * 64 >= n) return;

  constexpr int LDA = 66;
  __shared__ u16 Li[64 * LDA];
  __shared__ u16 Lj[64 * LDA];
  __shared__ float sqI[64], sqJ[64];

  const int tid = threadIdx.x;
  for (int e = tid; e < 1024; e += 256) {
    const int t = e >> 9;
    const int row = (e >> 3) & 63;
    const int ch = e & 7;
    const int g = (t ? tj : ti) * 64 + row;
    short8 v = (short8)0;
    if (g < n) {
      v = *(const short8*)(Ebf + (size_t)idx[start + g] * EMBN + ch * 8);
      if (ch == 0) { v[0] = 0; v[1] = 0; }
    }
    *(short8*)((t ? Lj : Li) + row * LDA + ch * 8) = v;
  }
  if (tid < 128) {
    const int t = tid >> 6, row = tid & 63;
    const int g = (t ? tj : ti) * 64 + row;
    (t ? sqJ : sqI)[row] = (g < n) ? sqrow[idx[start + g]] : 0.f;
  }
  __syncthreads();

  const int wave = tid >> 6, lane = tid & 63;
  const int wm = wave >> 1, wn = wave & 1;
  const int quad = lane >> 4, l15 = lane & 15;

  floatx4 acc[2][2];
#pragma unroll
  for (int i = 0; i < 2; ++i)
#pragma unroll
    for (int j = 0; j < 2; ++j) acc[i][j] = (floatx4){0.f, 0.f, 0.f, 0.f};

#pragma unroll
  for (int ks = 0; ks < 2; ++ks) {
    short8 af[2], bf[2];
#pragma unroll
    for (int i = 0; i < 2; ++i)
      af[i] = *(const short8*)(Li + (wm * 32 + i * 16 + l15) * LDA + ks * 32 + quad * 8);
#pragma unroll
    for (int j = 0; j < 2; ++j)
      bf[j] = *(const short8*)(Lj + (wn * 32 + j * 16 + l15) * LDA + ks * 32 + quad * 8);
#pragma unroll
    for (int i = 0; i < 2; ++i)
#pragma unroll
      for (int j = 0; j < 2; ++j)
        acc[i][j] = __builtin_amdgcn_mfma_f32_16x16x32_bf16(af[i], bf[j], acc[i][j], 0, 0, 0);
  }

  float local = 0.f;
#pragma unroll
  for (int i = 0; i < 2; ++i)
#pragma unroll
    for (int j = 0; j < 2; ++j)
#pragma unroll
      for (int r = 0; r < 4; ++r) {
        const int row = wm * 32 + i * 16 + quad * 4 + r;
        const int col = wn * 32 + j * 16 + l15;
        const int gi = ti * 64 + row, gj = tj * 64 + col;
        if (gi < n && gj < n && gi != gj) {
          const float D = (sqI[row] + sqJ[col] - 2.f * acc[i][j][r]) * (1.f / 62.f);
          local += fmaxf(0.f, MARGINF - D);
        }
      }
  if (ti < tj) local *= 2.f;

  __shared__ float red[256];
  red[tid] = local;
  __syncthreads();
  for (int st = 128; st > 0; st >>= 1) {
    if (tid < st) red[tid] += red[tid + st];
    __syncthreads();
  }
  if (tid == 0) atomicAdd(pair_sum, red[0]);
}

__device__ __forceinline__ double block_reduce_d(double v, double* red, int tid) {
  red[tid] = v;
  __syncthreads();
  for (int st = 128; st > 0; st >>= 1) {
    if (tid < st) red[tid] += red[tid + st];
    __syncthreads();
  }
  const double r = red[0];
  __syncthreads();
  return r;
}

// C_sim (factored, no N^2) and C_diff from pair_sum + analytic diagonal.
__global__ __launch_bounds__(256)
void finalize(const float* __restrict__ vsum, const float* __restrict__ Ssum,
              const int* __restrict__ counts, const float* __restrict__ pair_sum,
              float* __restrict__ out2)
{
  const int tid = threadIdx.x;
  __shared__ double red[256];

  double v = 0.0;
  if (tid < NCLS) v = (double)Ssum[tid] * (double)(NROWS - counts[tid]);
  const double t1 = block_reduce_d(v, red, tid);            // sum_c S_c (N - n_c)

  v = 0.0;
  if (tid < NCLS) { const double nc = (double)counts[tid]; v = nc * nc; }
  const double n_same = block_reduce_d(v, red, tid);        // sum n_c^2

  v = 0.0;
  for (int i = tid; i < NCLS * NCONS; i += 256) { const double w = vsum[i]; v += w * w; }
  const double t2 = block_reduce_d(v, red, tid);            // sum_c |v_c|^2

  v = 0.0;
  if (tid < NCONS) {
    double Vk = 0.0;
    for (int c = 0; c < NCLS; ++c) Vk += (double)vsum[c * NCONS + tid];
    v = Vk * Vk;
  }
  const double t3 = block_reduce_d(v, red, tid);            // |V|^2

  if (tid == 0) {
    const double n_diff = (double)NROWS * (double)NROWS - n_same;
    const double sim = 2.0 * t1 - 2.0 * (t3 - t2);
    const double C_sim = sim / 62.0 / (n_diff + 1.0);
    const double C_diff = ((double)pair_sum[0] + (double)NROWS * (double)MARGINF)
                          / (n_same + 1.0);
    out2[0] = (float)C_sim;
    out2[1] = (float)C_diff;
  }
}

// ---------------------------------------------------------------------------
// ws_size ~256 MB. Flat ~36 MB. 8 dispatches.
// ---------------------------------------------------------------------------
extern "C" void kernel_launch(void* const* d_in, const int* in_sizes, int n_in,
                              void* d_out, int out_size, void* d_ws, size_t ws_size,
                              hipStream_t stream)
{
  const float* x  = (const float*)d_in[0];
  const float* W1 = (const float*)d_in[1];
  const float* b1 = (const float*)d_in[2];
  const float* W2 = (const float*)d_in[3];
  const float* b2 = (const float*)d_in[4];
  const float* W3 = (const float*)d_in[5];
  const float* b3 = (const float*)d_in[6];
  const float* W4 = (const float*)d_in[7];
  const float* b4 = (const float*)d_in[8];
  float* out = (float*)d_out;

  char* ws = (char*)d_ws;
  const size_t KB = 1024, MB = 1ull << 20;
  u16* A0p    = (u16*)(ws + 0);                    // 8 MB packed A
  u16* W1p    = (u16*)(ws + 8 * MB);               // 1 MB
  u16* W2p    = (u16*)(ws + 9 * MB);               // 128 KB
  u16* W3p    = (u16*)(ws + 9 * MB + 128 * KB);    // 128 KB
  u16* W4p    = (u16*)(ws + 9 * MB + 256 * KB);    // 1 MB
  float* Ef4  = (float*)(ws + 10 * MB + 256 * KB); // 8 MB: 4 partial E buffers
  u16* Ebf    = (u16*)(ws + 18 * MB + 256 * KB);   // 1 MB
  int* labels = (int*)(ws + 19 * MB + 256 * KB);   // 32 KB
  int* idx    = (int*)(ws + 19 * MB + 288 * KB);   // 32 KB
  float* slab = (float*)(ws + 19 * MB + 320 * KB); // 16 KB (zeroed in prep_all)
  int*   counts  = (int*)slab;                     // [0,16)
  int*   offs    = counts + 16;                    // [16,33)
  float* Ssum    = (float*)(counts + 96);          // 16
  float* psum    = (float*)(counts + 128);         // 1
  float* vsum    = (float*)(counts + 256);         // 992
  float* sqrow = (float*)(ws + 19 * MB + 336 * KB);// 32 KB
  u16* T      = (u16*)(ws + 20 * MB);              // 16 MB (8192 x 1024 bf16)
  (void)in_sizes; (void)n_in; (void)out_size; (void)ws_size;

  prep_all<<<dim3(2625), dim3(256), 0, stream>>>(x, W1, W2, W3, W4,
                                                 A0p, W1p, W2p, W3p, W4p,
                                                 slab, labels);
  group_rows<<<dim3(1), dim3(256), 0, stream>>>(labels, offs, counts, idx);

  gemm12<<<dim3(128, 4), dim3(256), 0, stream>>>(A0p, W1p, b1, W2p, Ef4);
  stats_sq<<<dim3(128), dim3(256), 0, stream>>>(Ef4, b2, labels, Ebf, sqrow, vsum, Ssum);
  gemm3<<<dim3(4, 128), dim3(256), 0, stream>>>(Ebf, W3p, b3, T);
  gemm4<<<dim3(8, 64), dim3(256), 0, stream>>>(T, W4p, b4, out);
  pairwise_mfma<<<dim3(136, 16), dim3(256), 0, stream>>>(Ebf, sqrow, idx, offs, psum);
  finalize<<<dim3(1), dim3(256), 0, stream>>>(vsum, Ssum, counts, psum,
                                              out + (size_t)NROWS * DIN);
}